// Round 4
// baseline (997.363 us; speedup 1.0000x reference)
//
#include <hip/hip_runtime.h>

#define N_NODESC 100000
#define N_EDGESC 1600000
#define BN_EPSC 1e-5f
#define NBUCK 1024              // coarse buckets (dst>>7, 128 nodes each), 782 used
#define NUSED 782               // ceil(100000/128)
#define SBLK 256                // castsort blocks
#define EPB (N_EDGESC / SBLK)   // 6250 edges per block
#define MT 128                  // nodes per MLP block
#define BCAPG 2304              // global per-bucket stride (mean 1562, ~18 sigma)

// ---------------------------------------------------------------------------
// K_castsort: ONE preprocessing kernel.  (unchanged)
// packed = src(17b) | attr<<17(2b) | (dst&127)<<19(7b).
// ---------------------------------------------------------------------------
__global__ __launch_bounds__(1024) void k_castsort(
    const int* __restrict__ ei, const int* __restrict__ ea,
    const float* __restrict__ x, uint2* __restrict__ xh4,
    int* __restrict__ gcur, int* __restrict__ tmp)
{
    __shared__ int ledge[EPB + 22];     // 6272 sorted packed edges
    __shared__ int cnt[NBUCK];
    __shared__ int cstart[NBUCK + 1];
    __shared__ int cur[NBUCK];
    __shared__ int gofs[NBUCK];
    __shared__ int wtot[16];
    const int t = threadIdx.x;
    const int k = blockIdx.x;

    cnt[t] = 0;
    {   // ---- bf16 cast, batched ----
        const float4* x4 = (const float4*)x;
        const int g = k * 1024 + t;
        float4 v[7];
        bool m[7];
        #pragma unroll
        for (int i = 0; i < 7; i++) {
            const int idx = g + i * (SBLK * 1024);
            m[i] = (idx < N_NODESC * 16);
            if (m[i]) v[i] = x4[idx];
        }
        #pragma unroll
        for (int i = 0; i < 7; i++) {
            if (m[i]) {
                const int idx = g + i * (SBLK * 1024);
                unsigned int a = __float_as_uint(v[i].x);
                unsigned int b = __float_as_uint(v[i].y);
                unsigned int c = __float_as_uint(v[i].z);
                unsigned int d = __float_as_uint(v[i].w);
                a = (a + 0x7FFFu + ((a >> 16) & 1u)) >> 16;
                b = (b + 0x7FFFu + ((b >> 16) & 1u)) >> 16;
                c = (c + 0x7FFFu + ((c >> 16) & 1u)) >> 16;
                d = (d + 0x7FFFu + ((d >> 16) & 1u)) >> 16;
                xh4[idx] = make_uint2(a | (b << 16), c | (d << 16));
            }
        }
    }
    __syncthreads();        // cnt zeroed before counting

    int pk[7], bk[7];
    const int base = k * EPB;
    #pragma unroll
    for (int i = 0; i < 7; i++) {
        const int e = base + i * 1024 + t;
        if (e < base + EPB) {
            const int src = ei[e];
            const int dst = ei[N_EDGESC + e];
            const int a = ea[e];
            pk[i] = src | (a << 17) | ((dst & 127) << 19);
            bk[i] = dst >> 7;
            atomicAdd(&cnt[bk[i]], 1);
        } else bk[i] = -1;
    }
    __syncthreads();

    {   // exclusive scan of 1024 counts
        const int lane = t & 63;
        const int w = t >> 6;
        const int v = cnt[t];
        int inc = v;
        #pragma unroll
        for (int d = 1; d < 64; d <<= 1) {
            const int u = __shfl_up(inc, d);
            if (lane >= d) inc += u;
        }
        if (lane == 63) wtot[w] = inc;
        __syncthreads();
        int add = 0;
        #pragma unroll
        for (int w2 = 0; w2 < 16; w2++) if (w2 < w) add += wtot[w2];
        const int ex = inc - v + add;
        cstart[t] = ex;
        cur[t] = ex;
        if (t == 1023) cstart[NBUCK] = ex + v;
    }
    __syncthreads();

    #pragma unroll
    for (int i = 0; i < 7; i++) {
        if (bk[i] >= 0) {
            const int pos = atomicAdd(&cur[bk[i]], 1);
            ledge[pos] = pk[i];
        }
    }
    {
        const int c = cnt[t];
        if (c > 0) gofs[t] = atomicAdd(&gcur[t], c);
    }
    __syncthreads();

    for (int i = t; i < EPB; i += 1024) {
        int lo = 0, hi = NBUCK;
        #pragma unroll
        for (int s = 0; s < 10; s++) {
            const int mid = (lo + hi) >> 1;
            if (cstart[mid] <= i) lo = mid; else hi = mid;
        }
        const int o = gofs[lo] + (i - cstart[lo]);
        if (o < BCAPG) tmp[lo * BCAPG + o] = ledge[i];
    }
}

static __device__ __forceinline__ float4 sel4(bool c, float4 a, float4 b) {
    return make_float4(c ? a.x : b.x, c ? a.y : b.y, c ? a.z : b.z, c ? a.w : b.w);
}

// ---------------------------------------------------------------------------
// K_aggmlp1 v2 — barrier-free fusion.
//  R3 lesson: the LDS-lin + __syncthreads A->B handoff serialized the two
//  phases (occ 27.5%, hbm 1.75TB/s).  Now each lane keeps its h_pre slice
//  (features q*8..q*8+7) in registers and computes PARTIAL dot products vs
//  ALL 64 W1 columns (float4 p[16], static indices).  3-level shfl_xor(1/2/4)
//  reduce inside the 8-lane group -> full h1 row in every lane; static
//  cndmask tree extracts the lane's own 2 float4s for the coalesced store.
//  BN sums: shfl_xor(8/16/32) + 16 unsafeAtomicAdds from 8 lanes/wave.
//  NO barrier after the sort: waves flow gather->GEMM independently, GEMM
//  VALU/LDS hides under the fabric-bound gather stream.
//  W1 staged in LDS q-major with 548-word q-stride: the 8 distinct per-q
//  addresses of each broadcast read hit 8 distinct 4-bank groups (548*4 B
//  mod 128 B = 16 B) -> conflict-free.
//  256 threads (4 waves): 782*4=3128 waves all co-resident under the VGPR
//  cap (~16 waves/CU at ~110 VGPR).  LDS 29.4 KB.
// ---------------------------------------------------------------------------
__global__ __launch_bounds__(256) void k_aggmlp1(
    const ushort* __restrict__ xh, const float* __restrict__ emb,
    const float* __restrict__ x, const float* __restrict__ epsp,
    const int* __restrict__ gcur, const int* __restrict__ tmp,
    const float* __restrict__ W1, const float* __restrict__ b1,
    float* __restrict__ out, float* __restrict__ cs, float* __restrict__ css)
{
    __shared__ int packedL[BCAPG];      // 9216B (was 2x oversized)
    __shared__ int cnt[128];
    __shared__ int cst[128];
    __shared__ int cur[128];
    __shared__ float emL[4][68];        // padded edge-emb table
    __shared__ float lWre[8 * 548];     // 17536B: W1, q-major, bank-spread
    const int t = threadIdx.x;
    const int b = blockIdx.x;
    const int start = b * BCAPG;

    {   // ---- stage W1 -> lWre[q*548 + kk*68 + c] (k = q*8+kk) ----------
        const float4* W4 = (const float4*)W1;
        float4* lw4 = (float4*)lWre;
        #pragma unroll
        for (int i = 0; i < 4; i++) {
            const int i4 = i * 256 + t;          // 0..1023
            const int k = i4 >> 4;               // W1 row
            const int cq = i4 & 15;              // col quad
            lw4[(k >> 3) * 137 + (k & 7) * 17 + cq] = W4[i4];
        }
    }
    int cntb = gcur[b];
    if (cntb > BCAPG) cntb = BCAPG;
    if (t < 128) cnt[t] = 0;
    emL[t >> 6][t & 63] = emb[t];
    __syncthreads();

    // pass 1: per-node counts
    for (int e = t; e < cntb; e += 256)
        atomicAdd(&cnt[(tmp[start + e] >> 19) & 127], 1);
    __syncthreads();
    if (t < 64) {   // scan 128 counts (two 64-lane halves)
        const int lane = t;
        const int v0 = cnt[lane];
        const int v1 = cnt[64 + lane];
        int i0 = v0, i1 = v1;
        #pragma unroll
        for (int d = 1; d < 64; d <<= 1) {
            const int u0 = __shfl_up(i0, d);
            const int u1 = __shfl_up(i1, d);
            if (lane >= d) { i0 += u0; i1 += u1; }
        }
        const int tot0 = __shfl(i0, 63);
        cst[lane] = i0 - v0;
        cst[64 + lane] = tot0 + i1 - v1;
        cur[lane] = i0 - v0;
        cur[64 + lane] = tot0 + i1 - v1;
    }
    __syncthreads();
    // pass 2: place node-sorted into LDS
    for (int e = t; e < cntb; e += 256) {
        const int p = tmp[start + e];
        const int pos = atomicAdd(&cur[(p >> 19) & 127], 1);
        if (pos < BCAPG) packedL[pos] = p;
    }
    __syncthreads();    // LAST barrier — everything below is wave-local

    // ---- per-lane setup: group g owns nodes g*4..g*4+3; lane q = octet --
    const int g = t >> 3;                // 0..31
    const int q = t & 7;                 // features [q*8, q*8+8)
    const float sc1 = 1.0f + epsp[0];
    const uint4* xv8 = (const uint4*)xh;
    const float4* x4 = (const float4*)x;
    float4* o4 = (float4*)out;
    const float* eq = &emL[0][0] + q * 8;
    const float4* lw4r = ((const float4*)lWre) + q * 137;
    const float4* b4 = (const float4*)b1;
    const float4 bb0 = b4[q * 2 + 0];
    const float4 bb1 = b4[q * 2 + 1];
    const bool s0 = (q & 1) != 0;
    const bool s1 = (q & 2) != 0;
    const bool s2 = (q & 4) != 0;

    float vs[8], vq[8];
    #pragma unroll
    for (int c = 0; c < 8; c++) { vs[c] = 0.f; vq[c] = 0.f; }

    for (int j = 0; j < 4; j++) {
        const int nl = g * 4 + j;
        const int n = b * 128 + nl;
        int e = cst[nl];
        const int ee = cur[nl];           // cur == end after pass 2
        float4 aL = make_float4(0.f, 0.f, 0.f, 0.f);
        float4 aH = make_float4(0.f, 0.f, 0.f, 0.f);
        if (n < N_NODESC) {
            const float4 v0 = x4[(size_t)n * 16 + q * 2];
            const float4 v1 = x4[(size_t)n * 16 + q * 2 + 1];
            aL.x = sc1 * v0.x; aL.y = sc1 * v0.y;
            aL.z = sc1 * v0.z; aL.w = sc1 * v0.w;
            aH.x = sc1 * v1.x; aH.y = sc1 * v1.y;
            aH.z = sc1 * v1.z; aH.w = sc1 * v1.w;
        }
        // ---- gather + message accumulate (unroll-2 for ILP) ----
        for (; e + 2 <= ee; e += 2) {
            const int p0 = packedL[e];
            const int p1 = packedL[e + 1];
            const uint4 u0 = xv8[(size_t)(p0 & 0x1FFFF) * 8 + q];
            const uint4 u1 = xv8[(size_t)(p1 & 0x1FFFF) * 8 + q];
            const float* e0 = eq + ((p0 >> 17) & 3) * 68;
            const float* e1 = eq + ((p1 >> 17) & 3) * 68;
            const float4 t0L = *(const float4*)(e0);
            const float4 t0H = *(const float4*)(e0 + 4);
            const float4 t1L = *(const float4*)(e1);
            const float4 t1H = *(const float4*)(e1 + 4);
            aL.x += fmaxf(__uint_as_float(u0.x << 16)          + t0L.x, 0.f)
                  + fmaxf(__uint_as_float(u1.x << 16)          + t1L.x, 0.f);
            aL.y += fmaxf(__uint_as_float(u0.x & 0xFFFF0000u)  + t0L.y, 0.f)
                  + fmaxf(__uint_as_float(u1.x & 0xFFFF0000u)  + t1L.y, 0.f);
            aL.z += fmaxf(__uint_as_float(u0.y << 16)          + t0L.z, 0.f)
                  + fmaxf(__uint_as_float(u1.y << 16)          + t1L.z, 0.f);
            aL.w += fmaxf(__uint_as_float(u0.y & 0xFFFF0000u)  + t0L.w, 0.f)
                  + fmaxf(__uint_as_float(u1.y & 0xFFFF0000u)  + t1L.w, 0.f);
            aH.x += fmaxf(__uint_as_float(u0.z << 16)          + t0H.x, 0.f)
                  + fmaxf(__uint_as_float(u1.z << 16)          + t1H.x, 0.f);
            aH.y += fmaxf(__uint_as_float(u0.z & 0xFFFF0000u)  + t0H.y, 0.f)
                  + fmaxf(__uint_as_float(u1.z & 0xFFFF0000u)  + t1H.y, 0.f);
            aH.z += fmaxf(__uint_as_float(u0.w << 16)          + t0H.z, 0.f)
                  + fmaxf(__uint_as_float(u1.w << 16)          + t1H.z, 0.f);
            aH.w += fmaxf(__uint_as_float(u0.w & 0xFFFF0000u)  + t0H.w, 0.f)
                  + fmaxf(__uint_as_float(u1.w & 0xFFFF0000u)  + t1H.w, 0.f);
        }
        for (; e < ee; e++) {
            const int p0 = packedL[e];
            const uint4 u0 = xv8[(size_t)(p0 & 0x1FFFF) * 8 + q];
            const float* e0 = eq + ((p0 >> 17) & 3) * 68;
            const float4 t0L = *(const float4*)(e0);
            const float4 t0H = *(const float4*)(e0 + 4);
            aL.x += fmaxf(__uint_as_float(u0.x << 16)         + t0L.x, 0.f);
            aL.y += fmaxf(__uint_as_float(u0.x & 0xFFFF0000u) + t0L.y, 0.f);
            aL.z += fmaxf(__uint_as_float(u0.y << 16)         + t0L.z, 0.f);
            aL.w += fmaxf(__uint_as_float(u0.y & 0xFFFF0000u) + t0L.w, 0.f);
            aH.x += fmaxf(__uint_as_float(u0.z << 16)         + t0H.x, 0.f);
            aH.y += fmaxf(__uint_as_float(u0.z & 0xFFFF0000u) + t0H.y, 0.f);
            aH.z += fmaxf(__uint_as_float(u0.w << 16)         + t0H.z, 0.f);
            aH.w += fmaxf(__uint_as_float(u0.w & 0xFFFF0000u) + t0H.w, 0.f);
        }

        // ---- register GEMM: partials vs all 64 cols (this lane's 8 k's) -
        float4 p[16];
        #pragma unroll
        for (int cc = 0; cc < 16; cc++) p[cc] = make_float4(0.f, 0.f, 0.f, 0.f);
        const float hk[8] = {aL.x, aL.y, aL.z, aL.w, aH.x, aH.y, aH.z, aH.w};
        #pragma unroll
        for (int kk = 0; kk < 8; kk++) {
            const float h = hk[kk];
            #pragma unroll
            for (int cc = 0; cc < 16; cc++) {
                const float4 w = lw4r[kk * 17 + cc];
                p[cc].x = fmaf(h, w.x, p[cc].x);
                p[cc].y = fmaf(h, w.y, p[cc].y);
                p[cc].z = fmaf(h, w.z, p[cc].z);
                p[cc].w = fmaf(h, w.w, p[cc].w);
            }
        }
        // ---- reduce across the 8-lane group (k-dimension) ----
        #pragma unroll
        for (int m = 1; m < 8; m <<= 1) {
            #pragma unroll
            for (int cc = 0; cc < 16; cc++) {
                p[cc].x += __shfl_xor(p[cc].x, m);
                p[cc].y += __shfl_xor(p[cc].y, m);
                p[cc].z += __shfl_xor(p[cc].z, m);
                p[cc].w += __shfl_xor(p[cc].w, m);
            }
        }
        // ---- static extraction: lane q keeps col-quads 2q, 2q+1 ----
        float4 A[8];
        #pragma unroll
        for (int i = 0; i < 8; i++) A[i] = sel4(s2, p[i + 8], p[i]);
        float4 C[4];
        #pragma unroll
        for (int i = 0; i < 4; i++) C[i] = sel4(s1, A[i + 4], A[i]);
        float4 r0 = sel4(s0, C[2], C[0]);
        float4 r1 = sel4(s0, C[3], C[1]);
        r0.x += bb0.x; r0.y += bb0.y; r0.z += bb0.z; r0.w += bb0.w;
        r1.x += bb1.x; r1.y += bb1.y; r1.z += bb1.z; r1.w += bb1.w;
        const float mk = (n < N_NODESC) ? 1.0f : 0.0f;
        if (n < N_NODESC) {
            o4[(size_t)n * 16 + q * 2 + 0] = r0;
            o4[(size_t)n * 16 + q * 2 + 1] = r1;
        }
        const float h8[8] = {r0.x, r0.y, r0.z, r0.w, r1.x, r1.y, r1.z, r1.w};
        #pragma unroll
        for (int c = 0; c < 8; c++) {
            const float v = h8[c] * mk;
            vs[c] += v;
            vq[c] += v * h8[c];
        }
    }

    // ---- BN sums: wave-level reduce, 8 lanes/wave do the atomics --------
    #pragma unroll
    for (int m = 8; m < 64; m <<= 1) {
        #pragma unroll
        for (int c = 0; c < 8; c++) {
            vs[c] += __shfl_xor(vs[c], m);
            vq[c] += __shfl_xor(vq[c], m);
        }
    }
    if ((t & 63) < 8) {
        #pragma unroll
        for (int c = 0; c < 8; c++) {
            unsafeAtomicAdd(&cs[q * 8 + c], vs[c]);
            unsafeAtomicAdd(&css[q * 8 + c], vq[c]);
        }
    }
}

// ---------------------------------------------------------------------------
// K_mlp2: out = relu(BN(h1)) @ W2 + b2.  h1 aliases out; LDS-staged.
// ---------------------------------------------------------------------------
__global__ __launch_bounds__(256) void k_mlp2(
    const float* h1, const float* __restrict__ W2, const float* __restrict__ b2,
    const float* __restrict__ gamma, const float* __restrict__ beta,
    const float* __restrict__ cs, const float* __restrict__ css,
    float* out)
{
    __shared__ float lin[MT][68];
    __shared__ float lW[4096];
    __shared__ float scl[64];
    __shared__ float sft[64];
    const int t = threadIdx.x;
    const int nbase = blockIdx.x * MT;

    if (t < 64) {
        const float inv = 1.0f / (float)N_NODESC;
        const float mu = cs[t] * inv;
        const float var = css[t] * inv - mu * mu;
        const float rs = rsqrtf(var + BN_EPSC);
        const float s = rs * gamma[t];
        scl[t] = s;
        sft[t] = fmaf(-mu, s, beta[t]);
    }
    {
        const float4* W4 = (const float4*)W2;
        float4* lW4 = (float4*)lW;
        #pragma unroll
        for (int i = 0; i < 4; i++) lW4[i * 256 + t] = W4[i * 256 + t];
    }
    __syncthreads();
    {
        const float4* h4 = (const float4*)h1;
        #pragma unroll
        for (int i = 0; i < 8; i++) {
            const int fidx = i * 256 + t;
            const int row = fidx >> 4;
            const int q = fidx & 15;
            const int n = nbase + row;
            float4 v = make_float4(0.f, 0.f, 0.f, 0.f);
            if (n < N_NODESC) {
                const float4 h = h4[(size_t)n * 16 + q];
                const int c = q * 4;
                v.x = fmaxf(fmaf(h.x, scl[c + 0], sft[c + 0]), 0.f);
                v.y = fmaxf(fmaf(h.y, scl[c + 1], sft[c + 1]), 0.f);
                v.z = fmaxf(fmaf(h.z, scl[c + 2], sft[c + 2]), 0.f);
                v.w = fmaxf(fmaf(h.w, scl[c + 3], sft[c + 3]), 0.f);
            }
            *(float4*)&lin[row][q * 4] = v;
        }
    }
    __syncthreads();

    const int g = t & 7;
    const int r0 = t >> 3;
    const float4* lW4 = (const float4*)lW;
    const float4* b4 = (const float4*)b2;
    const float4 bb0 = b4[g * 2 + 0];
    const float4 bb1 = b4[g * 2 + 1];
    float4 a00 = bb0, a01 = bb1, a10 = bb0, a11 = bb1;
    float4 a20 = bb0, a21 = bb1, a30 = bb0, a31 = bb1;
    for (int k = 0; k < 64; k++) {
        const float v0 = lin[r0][k];
        const float v1 = lin[r0 + 32][k];
        const float v2 = lin[r0 + 64][k];
        const float v3 = lin[r0 + 96][k];
        const float4 w0 = lW4[k * 16 + g * 2 + 0];
        const float4 w1 = lW4[k * 16 + g * 2 + 1];
        a00.x = fmaf(v0, w0.x, a00.x); a00.y = fmaf(v0, w0.y, a00.y);
        a00.z = fmaf(v0, w0.z, a00.z); a00.w = fmaf(v0, w0.w, a00.w);
        a01.x = fmaf(v0, w1.x, a01.x); a01.y = fmaf(v0, w1.y, a01.y);
        a01.z = fmaf(v0, w1.z, a01.z); a01.w = fmaf(v0, w1.w, a01.w);
        a10.x = fmaf(v1, w0.x, a10.x); a10.y = fmaf(v1, w0.y, a10.y);
        a10.z = fmaf(v1, w0.z, a10.z); a10.w = fmaf(v1, w0.w, a10.w);
        a11.x = fmaf(v1, w1.x, a11.x); a11.y = fmaf(v1, w1.y, a11.y);
        a11.z = fmaf(v1, w1.z, a11.z); a11.w = fmaf(v1, w1.w, a11.w);
        a20.x = fmaf(v2, w0.x, a20.x); a20.y = fmaf(v2, w0.y, a20.y);
        a20.z = fmaf(v2, w0.z, a20.z); a20.w = fmaf(v2, w0.w, a20.w);
        a21.x = fmaf(v2, w1.x, a21.x); a21.y = fmaf(v2, w1.y, a21.y);
        a21.z = fmaf(v2, w1.z, a21.z); a21.w = fmaf(v2, w1.w, a21.w);
        a30.x = fmaf(v3, w0.x, a30.x); a30.y = fmaf(v3, w0.y, a30.y);
        a30.z = fmaf(v3, w0.z, a30.z); a30.w = fmaf(v3, w0.w, a30.w);
        a31.x = fmaf(v3, w1.x, a31.x); a31.y = fmaf(v3, w1.y, a31.y);
        a31.z = fmaf(v3, w1.z, a31.z); a31.w = fmaf(v3, w1.w, a31.w);
    }
    const float4 A0[4] = {a00, a10, a20, a30};
    const float4 A1[4] = {a01, a11, a21, a31};
    float4* o4 = (float4*)out;
    #pragma unroll
    for (int j = 0; j < 4; j++) {
        const int n = nbase + r0 + 32 * j;
        if (n < N_NODESC) {
            o4[(size_t)n * 16 + g * 2 + 0] = A0[j];
            o4[(size_t)n * 16 + g * 2 + 1] = A1[j];
        }
    }
}

// ---------------------------------------------------------------------------
extern "C" void kernel_launch(void* const* d_in, const int* in_sizes, int n_in,
                              void* d_out, int out_size, void* d_ws, size_t ws_size,
                              hipStream_t stream) {
    const float* x     = (const float*)d_in[0];
    const float* emb   = (const float*)d_in[1];
    const float* eps   = (const float*)d_in[2];
    const float* W1    = (const float*)d_in[3];
    const float* b1    = (const float*)d_in[4];
    const float* gamma = (const float*)d_in[5];
    const float* beta  = (const float*)d_in[6];
    const float* W2    = (const float*)d_in[7];
    const float* b2    = (const float*)d_in[8];
    const int*   ei    = (const int*)d_in[9];
    const int*   ea    = (const int*)d_in[10];
    float* out = (float*)d_out;

    // ws: [cs 64][css 64][gcur NBUCK][tmp NBUCK*BCAPG][xh N*64 bf16]  (~22 MB)
    float* ws    = (float*)d_ws;
    float* cs    = ws;
    float* css   = ws + 64;
    int*   gcur  = (int*)(ws + 128);
    int*   tmp   = gcur + NBUCK;
    ushort* xh   = (ushort*)(tmp + (size_t)NBUCK * BCAPG);

    // zero cs/css/gcur (4.6 KB)
    hipMemsetAsync(d_ws, 0, (size_t)(128 + NBUCK) * sizeof(int), stream);

    k_castsort<<<SBLK, 1024, 0, stream>>>(ei, ea, x, (uint2*)xh, gcur, tmp);
    k_aggmlp1<<<NUSED, 256, 0, stream>>>(xh, emb, x, eps, gcur, tmp,
                                         W1, b1, out, cs, css);   // h1 -> d_out
    k_mlp2<<<NUSED, 256, 0, stream>>>(out, W2, b2, gamma, beta, cs, css, out);
}